// Round 3
// baseline (104.728 us; speedup 1.0000x reference)
//
#include <hip/hip_runtime.h>

#define NITER 25

// Exact mirror of the reference: per-thread fp64, full 6x6 KKT matrix,
// partial-pivot Gaussian elimination fully unrolled in registers.
// (Analytic Schur/Cramer reduction NaN'd on degenerate elements where the
//  -1e-12 frac-to-boundary threshold lets lam step slightly negative; the
//  pivoted LU on the full finite K stays finite like numpy's dgesv.)
__global__ __launch_bounds__(256) void lcp_kernel(
    const float* __restrict__ pv, const float* __restrict__ mu_p,
    float* __restrict__ out, int n)
{
    int i = blockIdx.x * blockDim.x + threadIdx.x;
    if (i >= n) return;
    const double mu = (double)mu_p[0];
    const double SIG = 0.1;
    const double BIGD = 1.0e12;

    const float2 v = ((const float2*)pv)[i];
    const double q0 = -(double)v.x - 2.0;   // q = -v + (-2, 1), MASS=1
    const double q1 = -(double)v.y + 1.0;

    double z0 = -q0, z1 = -q1;
    double lam[4] = {1.0, 1.0, 1.0, 1.0};
    double s[4]   = {1.0, 1.0, 1.0, 1.0};

    for (int it = 0; it < NITER; ++it) {
        // residuals (same formulas/order as reference)
        double rd0 = z0 + q0 + (lam[1] - lam[2]);
        double rd1 = z1 + q1 - lam[0];
        double rp[4];
        rp[0] = -z1 + s[0];
        rp[1] =  z0 + s[1] - lam[3];
        rp[2] = -z0 + s[2] - lam[3];
        rp[3] =  s[3] - (mu * lam[0] - lam[1] - lam[2]);

        double sl0 = s[0]*lam[0], sl1 = s[1]*lam[1], sl2 = s[2]*lam[2], sl3 = s[3]*lam[3];
        double muc = 0.25 * (sl0 + sl1 + sl2 + sl3);
        double rc[4] = { sl0 - SIG*muc, sl1 - SIG*muc, sl2 - SIG*muc, sl3 - SIG*muc };

        double D[4];
        #pragma unroll
        for (int k = 0; k < 4; ++k) D[k] = s[k] / lam[k];

        // Augmented 6x7 system M * d = rhs
        // K = [[I2, G^T],[G, -(F + D*I)]],
        // G=[[0,-1],[1,0],[-1,0],[0,0]], F=[[0,0,0,0],[0,0,0,1],[0,0,0,1],[mu,-1,-1,0]]
        double M[6][7];
        M[0][0]=1.0;  M[0][1]=0.0;  M[0][2]=0.0;   M[0][3]=1.0;   M[0][4]=-1.0;  M[0][5]=0.0;   M[0][6]=-rd0;
        M[1][0]=0.0;  M[1][1]=1.0;  M[1][2]=-1.0;  M[1][3]=0.0;   M[1][4]=0.0;   M[1][5]=0.0;   M[1][6]=-rd1;
        M[2][0]=0.0;  M[2][1]=-1.0; M[2][2]=-D[0]; M[2][3]=0.0;   M[2][4]=0.0;   M[2][5]=0.0;   M[2][6]=-rp[0] + rc[0]/lam[0];
        M[3][0]=1.0;  M[3][1]=0.0;  M[3][2]=0.0;   M[3][3]=-D[1]; M[3][4]=0.0;   M[3][5]=-1.0;  M[3][6]=-rp[1] + rc[1]/lam[1];
        M[4][0]=-1.0; M[4][1]=0.0;  M[4][2]=0.0;   M[4][3]=0.0;   M[4][4]=-D[2]; M[4][5]=-1.0;  M[4][6]=-rp[2] + rc[2]/lam[2];
        M[5][0]=0.0;  M[5][1]=0.0;  M[5][2]=-mu;   M[5][3]=1.0;   M[5][4]=1.0;   M[5][5]=-D[3]; M[5][6]=-rp[3] + rc[3]/lam[3];

        // Partial-pivot Gaussian elimination, fully unrolled (registers only).
        #pragma unroll
        for (int k = 0; k < 6; ++k) {
            // bubble max-|pivot| row up to row k (value-equivalent to LAPACK swap)
            #pragma unroll
            for (int j = k + 1; j < 6; ++j) {
                bool sw = fabs(M[j][k]) > fabs(M[k][k]);
                #pragma unroll
                for (int c = k; c < 7; ++c) {
                    double a = M[k][c], b = M[j][c];
                    M[k][c] = sw ? b : a;
                    M[j][c] = sw ? a : b;
                }
            }
            double piv = M[k][k];
            #pragma unroll
            for (int j = k + 1; j < 6; ++j) {
                double f = M[j][k] / piv;
                #pragma unroll
                for (int c = k + 1; c < 7; ++c) M[j][c] -= f * M[k][c];
            }
        }
        // back-substitution
        double d[6];
        #pragma unroll
        for (int k = 5; k >= 0; --k) {
            double acc = M[k][6];
            #pragma unroll
            for (int c = k + 1; c < 6; ++c) acc -= M[k][c] * d[c];
            d[k] = acc / M[k][k];
        }

        double dz0 = d[0], dz1 = d[1];
        double dl[4] = { d[2], d[3], d[4], d[5] };

        double ds[4];
        ds[0] = -rp[0] + dz1;
        ds[1] = -rp[1] - dz0 + dl[3];
        ds[2] = -rp[2] + dz0 + dl[3];
        ds[3] = -rp[3] + (mu * dl[0] - dl[1] - dl[2]);

        // fraction-to-boundary (threshold semantics identical to reference)
        double amin = BIGD;
        #pragma unroll
        for (int k = 0; k < 4; ++k)
            amin = fmin(amin, (dl[k] < -1e-12) ? (-lam[k] / dl[k]) : BIGD);
        #pragma unroll
        for (int k = 0; k < 4; ++k)
            amin = fmin(amin, (ds[k] < -1e-12) ? (-s[k] / ds[k]) : BIGD);
        double alpha = fmin(1.0, 0.99 * amin);

        z0 += alpha * dz0;
        z1 += alpha * dz1;
        #pragma unroll
        for (int k = 0; k < 4; ++k) { lam[k] += alpha * dl[k]; s[k] += alpha * ds[k]; }
    }

    ((float2*)out)[i] = make_float2((float)z0, (float)z1);
}

extern "C" void kernel_launch(void* const* d_in, const int* in_sizes, int n_in,
                              void* d_out, int out_size, void* d_ws, size_t ws_size,
                              hipStream_t stream) {
    const float* pv = (const float*)d_in[0];
    const float* mu = (const float*)d_in[1];
    float* out = (float*)d_out;
    int n = in_sizes[0] / 2;  // B = 131072
    int block = 256;
    int grid = (n + block - 1) / block;
    lcp_kernel<<<grid, block, 0, stream>>>(pv, mu, out, n);
}

// Round 5
// 87.233 us; speedup vs baseline: 1.2006x; 1.2006x over previous
//
#include <hip/hip_runtime.h>

#define NITER 25

// fp64 rcp via v_rcp_f64 + 2 Newton refinements (~1 ulp), ~5 ops vs ~13 for
// the IEEE div sequence. clang spells the f64 builtin __builtin_amdgcn_rcp.
__device__ __forceinline__ double fast_rcp(double x) {
#if __has_builtin(__builtin_amdgcn_rcp)
    double r = __builtin_amdgcn_rcp(x);
    r = fma(fma(-x, r, 1.0), r, r);
    r = fma(fma(-x, r, 1.0), r, r);
    return r;
#else
    return 1.0 / x;
#endif
}

// Per-thread fp64 interior-point LCP, 25 iterations.
// The 6x6 KKT system's first two columns provably never pivot (candidate
// magnitudes are {0, 1} with LAPACK first-max tie-breaking), so they are
// eliminated symbolically, leaving the 4x4 Schur system
//   [[1+D0, 0,    0,    0 ],   [b0]
//    [0,    1+D1, -1,   1 ], = [b1]
//    [0,   -1,    1+D2, 1 ],   [b2]
//    [mu,  -1,   -1,    D3]]   [b3]
// solved with partial-pivot GE (pivoting is what keeps degenerate
// trajectory elements finite — unpivoted Cramer NaN'd in round 2).
__global__ __launch_bounds__(256) void lcp_kernel(
    const float* __restrict__ pv, const float* __restrict__ mu_p,
    float* __restrict__ out, int n)
{
    int i = blockIdx.x * blockDim.x + threadIdx.x;
    if (i >= n) return;
    const double mu = (double)mu_p[0];
    const double SIG = 0.1;

    const float2 v = ((const float2*)pv)[i];
    const double q0 = -(double)v.x - 2.0;   // q = -v + (-2, 1), MASS=1
    const double q1 = -(double)v.y + 1.0;

    double z0 = -q0, z1 = -q1;
    double lam[4] = {1.0, 1.0, 1.0, 1.0};
    double s[4]   = {1.0, 1.0, 1.0, 1.0};

    for (int it = 0; it < NITER; ++it) {
        // residuals (same formulas as reference)
        double rd0 = z0 + q0 + (lam[1] - lam[2]);
        double rd1 = z1 + q1 - lam[0];
        double rp0 = -z1 + s[0];
        double rp1 =  z0 + s[1] - lam[3];
        double rp2 = -z0 + s[2] - lam[3];
        double rp3 =  s[3] - (mu * lam[0] - lam[1] - lam[2]);

        double sl0 = s[0]*lam[0], sl1 = s[1]*lam[1], sl2 = s[2]*lam[2], sl3 = s[3]*lam[3];
        double muc = 0.25 * (sl0 + sl1 + sl2 + sl3);

        double il0 = fast_rcp(lam[0]), il1 = fast_rcp(lam[1]);
        double il2 = fast_rcp(lam[2]), il3 = fast_rcp(lam[3]);
        double D0 = s[0]*il0, D1 = s[1]*il1, D2 = s[2]*il2, D3 = s[3]*il3;

        // b = r_pri - r_cent/lam - G*r_dual   (Schur rhs)
        double b0 = rp0 - (sl0 - SIG*muc)*il0 + rd1;
        double b1 = rp1 - (sl1 - SIG*muc)*il1 - rd0;
        double b2 = rp2 - (sl2 - SIG*muc)*il2 + rd0;
        double b3 = rp3 - (sl3 - SIG*muc)*il3;

        // 4x5 augmented Schur system, partial-pivot GE (registers only)
        double M[4][5];
        M[0][0]=1.0+D0; M[0][1]=0.0;    M[0][2]=0.0;    M[0][3]=0.0; M[0][4]=b0;
        M[1][0]=0.0;    M[1][1]=1.0+D1; M[1][2]=-1.0;   M[1][3]=1.0; M[1][4]=b1;
        M[2][0]=0.0;    M[2][1]=-1.0;   M[2][2]=1.0+D2; M[2][3]=1.0; M[2][4]=b2;
        M[3][0]=mu;     M[3][1]=-1.0;   M[3][2]=-1.0;   M[3][3]=D3;  M[3][4]=b3;

        double inv[4];
        #pragma unroll
        for (int k = 0; k < 4; ++k) {
            #pragma unroll
            for (int j = k + 1; j < 4; ++j) {
                bool sw = fabs(M[j][k]) > fabs(M[k][k]);
                #pragma unroll
                for (int c = k; c < 5; ++c) {
                    double a = M[k][c], b = M[j][c];
                    M[k][c] = sw ? b : a;
                    M[j][c] = sw ? a : b;
                }
            }
            double ip = fast_rcp(M[k][k]);
            inv[k] = ip;
            #pragma unroll
            for (int j = k + 1; j < 4; ++j) {
                double f = M[j][k] * ip;
                #pragma unroll
                for (int c = k + 1; c < 5; ++c) M[j][c] = fma(-f, M[k][c], M[j][c]);
            }
        }
        double dl3 = M[3][4] * inv[3];
        double dl2 = (M[2][4] - M[2][3]*dl3) * inv[2];
        double dl1 = (M[1][4] - M[1][2]*dl2 - M[1][3]*dl3) * inv[1];
        double dl0 = (M[0][4] - M[0][1]*dl1 - M[0][2]*dl2 - M[0][3]*dl3) * inv[0];

        // back-substitute into the eliminated rows
        double dz0 = -rd0 - dl1 + dl2;
        double dz1 = -rd1 + dl0;

        double ds0 = -rp0 + dz1;
        double ds1 = -rp1 - dz0 + dl3;
        double ds2 = -rp2 + dz0 + dl3;
        double ds3 = -rp3 + (mu * dl0 - dl1 - dl2);

        // fraction-to-boundary: condition in fp64 (matches reference branch),
        // ratio in fp32 (rel err ~6e-8, far inside the 150x error headroom)
        float amin = 3.0e12f;
        amin = fminf(amin, (dl0 < -1e-12) ? ((float)lam[0] / (float)(-dl0)) : 3.0e12f);
        amin = fminf(amin, (dl1 < -1e-12) ? ((float)lam[1] / (float)(-dl1)) : 3.0e12f);
        amin = fminf(amin, (dl2 < -1e-12) ? ((float)lam[2] / (float)(-dl2)) : 3.0e12f);
        amin = fminf(amin, (dl3 < -1e-12) ? ((float)lam[3] / (float)(-dl3)) : 3.0e12f);
        amin = fminf(amin, (ds0 < -1e-12) ? ((float)s[0] / (float)(-ds0)) : 3.0e12f);
        amin = fminf(amin, (ds1 < -1e-12) ? ((float)s[1] / (float)(-ds1)) : 3.0e12f);
        amin = fminf(amin, (ds2 < -1e-12) ? ((float)s[2] / (float)(-ds2)) : 3.0e12f);
        amin = fminf(amin, (ds3 < -1e-12) ? ((float)s[3] / (float)(-ds3)) : 3.0e12f);
        double alpha = fmin(1.0, 0.99 * (double)amin);

        z0 += alpha * dz0;
        z1 += alpha * dz1;
        lam[0] += alpha * dl0; lam[1] += alpha * dl1;
        lam[2] += alpha * dl2; lam[3] += alpha * dl3;
        s[0] += alpha * ds0; s[1] += alpha * ds1;
        s[2] += alpha * ds2; s[3] += alpha * ds3;
    }

    ((float2*)out)[i] = make_float2((float)z0, (float)z1);
}

extern "C" void kernel_launch(void* const* d_in, const int* in_sizes, int n_in,
                              void* d_out, int out_size, void* d_ws, size_t ws_size,
                              hipStream_t stream) {
    const float* pv = (const float*)d_in[0];
    const float* mu = (const float*)d_in[1];
    float* out = (float*)d_out;
    int n = in_sizes[0] / 2;  // B = 131072
    int block = 256;
    int grid = (n + block - 1) / block;
    lcp_kernel<<<grid, block, 0, stream>>>(pv, mu, out, n);
}

// Round 6
// 78.715 us; speedup vs baseline: 1.3305x; 1.1082x over previous
//
#include <hip/hip_runtime.h>

#define NITER 25

// fp64 rcp via v_rcp_f64 + 2 Newton refinements (~1 ulp), ~5 ops vs ~13 for
// the IEEE div sequence.
__device__ __forceinline__ double fast_rcp(double x) {
#if __has_builtin(__builtin_amdgcn_rcp)
    double r = __builtin_amdgcn_rcp(x);
    r = fma(fma(-x, r, 1.0), r, r);
    r = fma(fma(-x, r, 1.0), r, r);
    return r;
#else
    return 1.0 / x;
#endif
}

// fp32 rcp (v_rcp_f32, ~1 ulp) — used only for the fraction-to-boundary
// ratios, which decide alpha; 1e-7 relative error vs 150x error headroom.
__device__ __forceinline__ float fast_rcpf(float x) {
#if __has_builtin(__builtin_amdgcn_rcpf)
    return __builtin_amdgcn_rcpf(x);
#else
    return 1.0f / x;
#endif
}

// Per-thread fp64 interior-point LCP, 25 iterations.
// 6x6 KKT -> 4x4 Schur system (validated bit-identical to the full pivoted
// 6x6 GE in rounds 3/5):
//   [[1+D0, 0,    0,    0 ],   [b0]
//    [0,    1+D1, -1,   1 ], = [b1]
//    [0,   -1,    1+D2, 1 ],   [b2]
//    [mu,  -1,   -1,    D3]]   [b3]
// Column 0 has only two structural nonzeros (rows 0,3): one compare-swap +
// one row update, then a generic pivoted 3x3. Skipped updates multiply
// exact zeros, so results are value-identical to the full 4x4 pivoted GE.
__global__ __launch_bounds__(256) void lcp_kernel(
    const float* __restrict__ pv, const float* __restrict__ mu_p,
    float* __restrict__ out, int n)
{
    int i = blockIdx.x * blockDim.x + threadIdx.x;
    if (i >= n) return;
    const double mu = (double)mu_p[0];
    const double SIG = 0.1;

    const float2 v = ((const float2*)pv)[i];
    const double q0 = -(double)v.x - 2.0;   // q = -v + (-2, 1), MASS=1
    const double q1 = -(double)v.y + 1.0;

    double z0 = -q0, z1 = -q1;
    double lam[4] = {1.0, 1.0, 1.0, 1.0};
    double s[4]   = {1.0, 1.0, 1.0, 1.0};

    for (int it = 0; it < NITER; ++it) {
        // residuals (same formulas as reference)
        double rd0 = z0 + q0 + (lam[1] - lam[2]);
        double rd1 = z1 + q1 - lam[0];
        double rp0 = -z1 + s[0];
        double rp1 =  z0 + s[1] - lam[3];
        double rp2 = -z0 + s[2] - lam[3];
        double rp3 =  s[3] - (mu * lam[0] - lam[1] - lam[2]);

        double sl0 = s[0]*lam[0], sl1 = s[1]*lam[1], sl2 = s[2]*lam[2], sl3 = s[3]*lam[3];
        double muc = 0.25 * (sl0 + sl1 + sl2 + sl3);

        double il0 = fast_rcp(lam[0]), il1 = fast_rcp(lam[1]);
        double il2 = fast_rcp(lam[2]), il3 = fast_rcp(lam[3]);
        double D0 = s[0]*il0, D1 = s[1]*il1, D2 = s[2]*il2, D3 = s[3]*il3;

        // b = r_pri - r_cent/lam - G*r_dual   (Schur rhs)
        double b0 = rp0 - (sl0 - SIG*muc)*il0 + rd1;
        double b1 = rp1 - (sl1 - SIG*muc)*il1 - rd0;
        double b2 = rp2 - (sl2 - SIG*muc)*il2 + rd0;
        double b3 = rp3 - (sl3 - SIG*muc)*il3;

        // ---- column 0: candidates are rows 0 and 3 only ----
        double P0[5] = { 1.0 + D0, 0.0, 0.0, 0.0, b0 };
        double P3[5] = { mu, -1.0, -1.0, D3, b3 };
        {
            bool sw = fabs(P3[0]) > fabs(P0[0]);
            #pragma unroll
            for (int c = 0; c < 5; ++c) {
                double a = P0[c], b = P3[c];
                P0[c] = sw ? b : a;
                P3[c] = sw ? a : b;
            }
        }
        double ip0 = fast_rcp(P0[0]);
        {
            double f = P3[0] * ip0;
            #pragma unroll
            for (int c = 1; c < 5; ++c) P3[c] = fma(-f, P0[c], P3[c]);
        }

        // ---- pivoted 3x3 over cols 1..4: rows R1,R2,R3 ----
        double R1[4] = { 1.0 + D1, -1.0, 1.0, b1 };
        double R2[4] = { -1.0, 1.0 + D2, 1.0, b2 };
        double R3[4] = { P3[1], P3[2], P3[3], P3[4] };

        // col1 pivot among R1,R2,R3 (bubble max to R1)
        {
            bool sw = fabs(R2[0]) > fabs(R1[0]);
            #pragma unroll
            for (int c = 0; c < 4; ++c) { double a=R1[c], b=R2[c]; R1[c]=sw?b:a; R2[c]=sw?a:b; }
        }
        {
            bool sw = fabs(R3[0]) > fabs(R1[0]);
            #pragma unroll
            for (int c = 0; c < 4; ++c) { double a=R1[c], b=R3[c]; R1[c]=sw?b:a; R3[c]=sw?a:b; }
        }
        double ip1 = fast_rcp(R1[0]);
        {
            double f2 = R2[0] * ip1;
            double f3 = R3[0] * ip1;
            #pragma unroll
            for (int c = 1; c < 4; ++c) {
                R2[c] = fma(-f2, R1[c], R2[c]);
                R3[c] = fma(-f3, R1[c], R3[c]);
            }
        }
        // col2 pivot among R2,R3
        {
            bool sw = fabs(R3[1]) > fabs(R2[1]);
            #pragma unroll
            for (int c = 1; c < 4; ++c) { double a=R2[c], b=R3[c]; R2[c]=sw?b:a; R3[c]=sw?a:b; }
        }
        double ip2 = fast_rcp(R2[1]);
        {
            double f = R3[1] * ip2;
            R3[2] = fma(-f, R2[2], R3[2]);
            R3[3] = fma(-f, R2[3], R3[3]);
        }
        double ip3 = fast_rcp(R3[2]);

        // back-substitution
        double dl3 = R3[3] * ip3;
        double dl2 = (R2[3] - R2[2]*dl3) * ip2;
        double dl1 = (R1[3] - R1[1]*dl2 - R1[2]*dl3) * ip1;
        double dl0 = (P0[4] - P0[1]*dl1 - P0[2]*dl2 - P0[3]*dl3) * ip0;

        // eliminated-row back-substitution
        double dz0 = -rd0 - dl1 + dl2;
        double dz1 = -rd1 + dl0;

        double ds0 = -rp0 + dz1;
        double ds1 = -rp1 - dz0 + dl3;
        double ds2 = -rp2 + dz0 + dl3;
        double ds3 = -rp3 + (mu * dl0 - dl1 - dl2);

        // fraction-to-boundary: branch condition in fp64 (matches reference),
        // ratio in fp32 via v_rcp_f32
        float amin = 3.0e12f;
        amin = fminf(amin, (dl0 < -1e-12) ? ((float)lam[0] * fast_rcpf((float)(-dl0))) : 3.0e12f);
        amin = fminf(amin, (dl1 < -1e-12) ? ((float)lam[1] * fast_rcpf((float)(-dl1))) : 3.0e12f);
        amin = fminf(amin, (dl2 < -1e-12) ? ((float)lam[2] * fast_rcpf((float)(-dl2))) : 3.0e12f);
        amin = fminf(amin, (dl3 < -1e-12) ? ((float)lam[3] * fast_rcpf((float)(-dl3))) : 3.0e12f);
        amin = fminf(amin, (ds0 < -1e-12) ? ((float)s[0] * fast_rcpf((float)(-ds0))) : 3.0e12f);
        amin = fminf(amin, (ds1 < -1e-12) ? ((float)s[1] * fast_rcpf((float)(-ds1))) : 3.0e12f);
        amin = fminf(amin, (ds2 < -1e-12) ? ((float)s[2] * fast_rcpf((float)(-ds2))) : 3.0e12f);
        amin = fminf(amin, (ds3 < -1e-12) ? ((float)s[3] * fast_rcpf((float)(-ds3))) : 3.0e12f);
        double alpha = fmin(1.0, 0.99 * (double)amin);

        z0 += alpha * dz0;
        z1 += alpha * dz1;
        lam[0] += alpha * dl0; lam[1] += alpha * dl1;
        lam[2] += alpha * dl2; lam[3] += alpha * dl3;
        s[0] += alpha * ds0; s[1] += alpha * ds1;
        s[2] += alpha * ds2; s[3] += alpha * ds3;
    }

    ((float2*)out)[i] = make_float2((float)z0, (float)z1);
}

extern "C" void kernel_launch(void* const* d_in, const int* in_sizes, int n_in,
                              void* d_out, int out_size, void* d_ws, size_t ws_size,
                              hipStream_t stream) {
    const float* pv = (const float*)d_in[0];
    const float* mu = (const float*)d_in[1];
    float* out = (float*)d_out;
    int n = in_sizes[0] / 2;  // B = 131072
    int block = 256;
    int grid = (n + block - 1) / block;
    lcp_kernel<<<grid, block, 0, stream>>>(pv, mu, out, n);
}